// Round 1
// 690.655 us; speedup vs baseline: 1.0147x; 1.0147x over previous
//
#include <hip/hip_runtime.h>
#include <math.h>

#define IN_DIM 1433
#define KPAD 1472          // 23 * 64, zero-padded
#define H_TOPO 64
#define ALIGN 32
#define NCLS 7
#define NT 23              // ceil(1433/64), last tile has 25 valid k

typedef __attribute__((ext_vector_type(8))) short short8;
typedef __attribute__((ext_vector_type(4))) short short4v;
typedef __attribute__((ext_vector_type(4))) float floatx4;
typedef __attribute__((ext_vector_type(4))) unsigned int uint4v;
typedef float float4u __attribute__((ext_vector_type(4), aligned(4)));   // 4B-aligned float4
typedef float float4a __attribute__((ext_vector_type(4), aligned(16)));  // 16B-aligned float4

__device__ inline unsigned short f2bf(float f) {
    union { float f; unsigned u; } v; v.f = f;
    unsigned r = v.u + 0x7FFF + ((v.u >> 16) & 1);   // round-to-nearest-even
    return (unsigned short)(r >> 16);
}

// ---------------- degree histogram ----------------

__global__ void k_count(const int* __restrict__ ei, int* __restrict__ cnt, int E) {
    int e = blockIdx.x * blockDim.x + threadIdx.x;
    if (e < E) atomicAdd(&cnt[ei[E + e]], 1);
}

// ---------------- exclusive scan of cnt -> row_start (+ rsqrt fused) ----------------

__global__ void k_scan1(const int* __restrict__ cnt, int* __restrict__ part,
                        int* __restrict__ bsum, int n) {
    __shared__ int s[256];
    int t = threadIdx.x;
    int i = blockIdx.x * 256 + t;
    int v = (i < n) ? cnt[i] : 0;
    s[t] = v;
    __syncthreads();
    #pragma unroll
    for (int off = 1; off < 256; off <<= 1) {
        int x = (t >= off) ? s[t - off] : 0;
        __syncthreads();
        s[t] += x;
        __syncthreads();
    }
    if (i < n) part[i] = s[t] - v;          // exclusive within block
    if (t == 255) bsum[blockIdx.x] = s[255];
}

__global__ void k_scan2(int* __restrict__ bsum, int nb) {
    __shared__ int s[256];
    int t = threadIdx.x;
    int v = (t < nb) ? bsum[t] : 0;
    s[t] = v;
    __syncthreads();
    #pragma unroll
    for (int off = 1; off < 256; off <<= 1) {
        int x = (t >= off) ? s[t - off] : 0;
        __syncthreads();
        s[t] += x;
        __syncthreads();
    }
    if (t < nb) bsum[t] = s[t] - v;         // exclusive block offsets
}

__global__ void k_scan3(int* __restrict__ part, const int* __restrict__ bsum,
                        const int* __restrict__ cnt, int* __restrict__ cursor,
                        float* __restrict__ dis, int n) {
    int i = blockIdx.x * blockDim.x + threadIdx.x;
    if (i >= n) return;
    int v = part[i] + bsum[i >> 8];
    part[i] = v;        // becomes row_start
    cursor[i] = v;
    dis[i] = rsqrtf(1.0f + (float)cnt[i]);  // +1 self-loop
}

// ---------------- CSR fill: col[pos] = src, bucketed by dst ----------------

__global__ void k_fill(const int* __restrict__ ei, int* __restrict__ cursor,
                       int* __restrict__ col, int E) {
    int e = blockIdx.x * blockDim.x + threadIdx.x;
    if (e >= E) return;
    int dst = ei[E + e];
    int pos = atomicAdd(&cursor[dst], 1);
    col[pos] = ei[e];
}

// ---------------- W pre-transpose to bf16: wT[c][k] ----------------

__global__ void k_wprep(const float* __restrict__ Wg, const float* __restrict__ Wp,
                        unsigned short* __restrict__ wT) {
    int i = blockIdx.x * blockDim.x + threadIdx.x;
    if (i >= 96 * KPAD) return;
    int c = i / KPAD, k = i % KPAD;
    float v = 0.0f;
    if (k < IN_DIM) v = (c < 64) ? Wg[k * 64 + c] : Wp[k * 32 + (c - 64)];
    wT[i] = f2bf(v);
}

// ---------------- MFMA GEMM (reg-prefetch pipeline):
//  xwsb = bf16( (x@W_gcn)*dis ) ; agg = xw*dis^2 (f32 self term) ; zsem = x@W_ps + b_ps

#define BM 128
#define BK 64
#define APAD 72

__global__ __launch_bounds__(256) void k_gemm(
    const float* __restrict__ x, const unsigned short* __restrict__ wT,
    const float* __restrict__ bps, const float* __restrict__ dis,
    unsigned short* __restrict__ xwsb, float* __restrict__ agg,
    float* __restrict__ zsem, int n)
{
    __shared__ unsigned short a_lds[BM * APAD];   // 18432 B
    __shared__ unsigned short b_lds[96 * APAD];   // 13824 B

    int t = threadIdx.x;
    int row0 = blockIdx.x * BM;
    int w  = t >> 6;        // wave 0..3 -> rows w*32 .. w*32+31
    int l  = t & 63;
    int lm = l & 15;
    int lg = l >> 4;
    int c4 = t & 15;        // 16B chunk within row
    int rb = t >> 4;        // row within 16-row pass

    floatx4 acc[2][6] = {};
    float4u aPf[8];
    short8  bPf[3];

    auto load_tile = [&](int k0) {
        if (k0 + BK <= IN_DIM) {
            #pragma unroll
            for (int p = 0; p < 8; ++p) {
                int gr = row0 + p * 16 + rb;
                float4u v = {};
                if (gr < n) v = *(const float4u*)&x[(long)gr * IN_DIM + k0 + 4 * c4];
                aPf[p] = v;
            }
        } else {
            #pragma unroll
            for (int p = 0; p < 8; ++p) {
                int gr = row0 + p * 16 + rb;
                float4u v = {};
                if (gr < n) {
                    #pragma unroll
                    for (int q = 0; q < 4; ++q) {
                        int gk = k0 + 4 * c4 + q;
                        v[q] = (gk < IN_DIM) ? x[(long)gr * IN_DIM + gk] : 0.0f;
                    }
                }
                aPf[p] = v;
            }
        }
        #pragma unroll
        for (int it = 0; it < 3; ++it) {
            int idx = it * 256 + t;
            int c = idx >> 3, kc = (idx & 7) * 8;
            bPf[it] = *(const short8*)&wT[c * KPAD + k0 + kc];
        }
    };
    auto store_tile = [&]() {
        #pragma unroll
        for (int p = 0; p < 8; ++p) {
            short4v pv;
            pv.x = (short)f2bf(aPf[p].x); pv.y = (short)f2bf(aPf[p].y);
            pv.z = (short)f2bf(aPf[p].z); pv.w = (short)f2bf(aPf[p].w);
            *(short4v*)&a_lds[(p * 16 + rb) * APAD + 4 * c4] = pv;
        }
        #pragma unroll
        for (int it = 0; it < 3; ++it) {
            int idx = it * 256 + t;
            int c = idx >> 3, kc = (idx & 7) * 8;
            *(short8*)&b_lds[c * APAD + kc] = bPf[it];
        }
    };

    load_tile(0);
    store_tile();
    __syncthreads();

    for (int kt = 0; kt < NT; ++kt) {
        if (kt + 1 < NT) load_tile((kt + 1) * BK);   // global loads in flight over MFMA
        #pragma unroll
        for (int h = 0; h < 2; ++h) {
            int koff = h * 32 + lg * 8;
            short8 a0 = *(const short8*)&a_lds[(w * 32 + lm) * APAD + koff];
            short8 a1 = *(const short8*)&a_lds[(w * 32 + 16 + lm) * APAD + koff];
            #pragma unroll
            for (int j = 0; j < 6; ++j) {
                short8 bf = *(const short8*)&b_lds[(j * 16 + lm) * APAD + koff];
                acc[0][j] = __builtin_amdgcn_mfma_f32_16x16x32_bf16(a0, bf, acc[0][j], 0, 0, 0);
                acc[1][j] = __builtin_amdgcn_mfma_f32_16x16x32_bf16(a1, bf, acc[1][j], 0, 0, 0);
            }
        }
        __syncthreads();                 // all waves done reading LDS
        if (kt + 1 < NT) {
            store_tile();                // write prefetched tile
            __syncthreads();
        }
    }

    // epilogue: C layout col=lane&15, row=(lane>>4)*4+reg
    #pragma unroll
    for (int mt = 0; mt < 2; ++mt) {
        #pragma unroll
        for (int r = 0; r < 4; ++r) {
            int grow = row0 + w * 32 + mt * 16 + lg * 4 + r;
            if (grow >= n) continue;
            float d = dis[grow];
            #pragma unroll
            for (int j = 0; j < 6; ++j) {
                int c = j * 16 + lm;
                float v = acc[mt][j][r];
                if (c < 64) {
                    float s = v * d;                       // xw * dis[src], pre-scaled
                    xwsb[(long)grow * 64 + c] = f2bf(s);   // bf16 message payload
                    agg[(long)grow * 64 + c] = s * d;      // self-loop: xw * dis^2 (f32)
                } else {
                    zsem[(long)grow * 32 + (c - 64)] = v + bps[c - 64];
                }
            }
        }
    }
}

// ---------------- CSR pull: agg[dst] += dis[dst] * sum_{src in N(dst)} xwsb[src] ----
// one wave per dst; lane = (neighbor-slot ng 0..7, feature-octet f8 0..7)
// each lane gathers 16B (8 bf16) -> 8 rows of 128B per inner iteration

__global__ __launch_bounds__(256) void k_pull(
    const int* __restrict__ row_start, const int* __restrict__ cnt,
    const int* __restrict__ col, const unsigned short* __restrict__ xwsb,
    const float* __restrict__ dis, float* __restrict__ agg, int n)
{
    int t = threadIdx.x;
    int dst = (blockIdx.x * 256 + t) >> 6;
    int lane = t & 63;
    int ng = lane >> 3;     // neighbor slot 0..7
    int f8 = lane & 7;      // feature octet (features f8*8 .. f8*8+7)
    if (dst >= n) return;
    int s = row_start[dst];
    int c = cnt[dst];
    float acc[8] = {};
    for (int j0 = 0; j0 < c; j0 += 64) {
        int m = c - j0; if (m > 64) m = 64;
        int idx = (lane < m) ? col[s + j0 + lane] : -1;
        for (int j = 0; j < m; j += 8) {
            int sj = __shfl(idx, j + ng);          // j+ng <= 63 always
            if (sj >= 0) {
                uint4v v = *(const uint4v*)&xwsb[(long)sj * 64 + f8 * 8];
                #pragma unroll
                for (int q = 0; q < 4; ++q) {
                    acc[2 * q]     += __uint_as_float(v[q] << 16);
                    acc[2 * q + 1] += __uint_as_float(v[q] & 0xffff0000u);
                }
            }
        }
    }
    // reduce across the 8 neighbor slots (lane bits 3..5)
    #pragma unroll
    for (int q = 0; q < 8; ++q) {
        acc[q] += __shfl_xor(acc[q], 8);
        acc[q] += __shfl_xor(acc[q], 16);
        acc[q] += __shfl_xor(acc[q], 32);
    }
    if (ng == 0) {
        float dd = dis[dst];
        float4a* po = (float4a*)&agg[(long)dst * 64 + f8 * 8];
        float4a o0 = po[0], o1 = po[1];            // self-loop term already there
        o0.x += acc[0] * dd; o0.y += acc[1] * dd;
        o0.z += acc[2] * dd; o0.w += acc[3] * dd;
        o1.x += acc[4] * dd; o1.y += acc[5] * dd;
        o1.z += acc[6] * dd; o1.w += acc[7] * dd;
        po[0] = o0; po[1] = o1;
    }
}

// ---------------- per-node head ----------------

__global__ __launch_bounds__(256) void k_head(
    const float* __restrict__ agg, const float* __restrict__ bgcn,
    const float* __restrict__ Wpt, const float* __restrict__ bpt,
    const float* __restrict__ Wcls, const float* __restrict__ bcls,
    const float* __restrict__ zsem,
    float* __restrict__ logits, float* __restrict__ anom, float* __restrict__ ztopo,
    int n)
{
    __shared__ float sW[H_TOPO * ALIGN];
    __shared__ float sC[ALIGN * NCLS];
    __shared__ float sbp[ALIGN], sbc[NCLS], sbg[H_TOPO];
    int t = threadIdx.x;
    for (int i = t; i < H_TOPO * ALIGN; i += 256) sW[i] = Wpt[i];
    for (int i = t; i < ALIGN * NCLS; i += 256) sC[i] = Wcls[i];
    if (t < ALIGN) sbp[t] = bpt[t];
    if (t < NCLS) sbc[t] = bcls[t];
    if (t < H_TOPO) sbg[t] = bgcn[t];
    __syncthreads();

    long node = (long)blockIdx.x * 256 + t;
    if (node >= n) return;

    float h[H_TOPO];
    const float* arow = agg + node * H_TOPO;
    #pragma unroll
    for (int k = 0; k < H_TOPO; ++k) h[k] = fmaxf(arow[k] + sbg[k], 0.0f);

    float z[ALIGN];
    #pragma unroll
    for (int j = 0; j < ALIGN; ++j) z[j] = sbp[j];
    #pragma unroll 4
    for (int k = 0; k < H_TOPO; ++k) {
        float hk = h[k];
        #pragma unroll
        for (int j = 0; j < ALIGN; ++j) z[j] += hk * sW[k * ALIGN + j];
    }

    float lg[NCLS];
    #pragma unroll
    for (int c = 0; c < NCLS; ++c) lg[c] = sbc[c];
    #pragma unroll
    for (int j = 0; j < ALIGN; ++j) {
        float zj = z[j];
        #pragma unroll
        for (int c = 0; c < NCLS; ++c) lg[c] += zj * sC[j * NCLS + c];
    }

    float ss = 0.0f;
    const float* zs = zsem + node * ALIGN;
    #pragma unroll
    for (int j = 0; j < ALIGN; ++j) { float d = z[j] - zs[j]; ss += d * d; }

    #pragma unroll
    for (int c = 0; c < NCLS; ++c) logits[node * NCLS + c] = lg[c];
    anom[node] = sqrtf(ss);
    #pragma unroll
    for (int j = 0; j < ALIGN; ++j) ztopo[node * ALIGN + j] = z[j];
}

// ---------------- launch ----------------

extern "C" void kernel_launch(void* const* d_in, const int* in_sizes, int n_in,
                              void* d_out, int out_size, void* d_ws, size_t ws_size,
                              hipStream_t stream) {
    const float* x   = (const float*)d_in[0];
    const int*   ei  = (const int*)d_in[1];
    const float* Wg  = (const float*)d_in[2];
    const float* bg  = (const float*)d_in[3];
    const float* Wpt = (const float*)d_in[4];
    const float* bpt = (const float*)d_in[5];
    const float* Wps = (const float*)d_in[6];
    const float* bps = (const float*)d_in[7];
    const float* Wc  = (const float*)d_in[8];
    const float* bc  = (const float*)d_in[9];

    int n = in_sizes[0] / IN_DIM;   // 50000
    int E = in_sizes[1] / 2;        // 1600000
    int nb = (n + 255) / 256;       // 196

    float* out    = (float*)d_out;
    float* logits = out;
    float* anom   = logits + (long)n * NCLS;
    float* ztopo  = anom + n;
    float* zsem   = ztopo + (long)n * ALIGN;

    // workspace layout (16B-aligned chunks for n=50000, E=1600000)
    float* ws   = (float*)d_ws;
    float* agg  = ws;                               // n*64 f
    float* dis  = agg + (long)n * H_TOPO;           // n f
    int* cnt       = (int*)(dis + n);               // n
    int* row_start = cnt + n;                       // n
    int* cursor    = row_start + n;                 // n
    int* bsum      = cursor + n;                    // 256
    int* col       = bsum + 256;                    // E
    unsigned short* wT   = (unsigned short*)(col + E);  // 96*KPAD bf16
    unsigned short* xwsb = wT + 96 * KPAD;              // n*64 bf16 (16B aligned)

    hipMemsetAsync(cnt, 0, (size_t)n * sizeof(int), stream);
    k_count <<<(E + 255) / 256, 256, 0, stream>>>(ei, cnt, E);
    k_scan1 <<<nb, 256, 0, stream>>>(cnt, row_start, bsum, n);
    k_scan2 <<<1, 256, 0, stream>>>(bsum, nb);
    k_scan3 <<<nb, 256, 0, stream>>>(row_start, bsum, cnt, cursor, dis, n);
    k_fill  <<<(E + 255) / 256, 256, 0, stream>>>(ei, cursor, col, E);
    k_wprep <<<(96 * KPAD + 255) / 256, 256, 0, stream>>>(Wg, Wps, wT);
    k_gemm  <<<(n + BM - 1) / BM, 256, 0, stream>>>(x, wT, bps, dis, xwsb, agg, zsem, n);
    k_pull  <<<(n + 3) / 4, 256, 0, stream>>>(row_start, cnt, col, xwsb, dis, agg, n);
    k_head  <<<nb, 256, 0, stream>>>(agg, bg, Wpt, bpt, Wc, bc, zsem,
                                     logits, anom, ztopo, n);
}